// Round 6
// baseline (1090.619 us; speedup 1.0000x reference)
//
#include <hip/hip_runtime.h>

#define N_NODES 100000
#define N_EDGES 1600000
#define HID 128
#define N_GNN 3
#define OUT_CH 2
#define EPS 1e-12f

#define SCAN_BLOCK 256
#define SCAN_ITEMS 8
#define SCAN_CHUNK 2048  // SCAN_BLOCK * SCAN_ITEMS
#define SCAN_NBLOCKS ((N_NODES + SCAN_CHUNK - 1) / SCAN_CHUNK)  // 49

// ---------------------------------------------------------------------------
// integer in-degree
__global__ void k_deg(const int* __restrict__ dst, int* __restrict__ deg, int E) {
    int i = blockIdx.x * blockDim.x + threadIdx.x;
    if (i < E) atomicAdd(&deg[dst[i]], 1);
}

// Per-block exclusive scan of deg into offs (block-local), block totals to bsum.
__global__ __launch_bounds__(SCAN_BLOCK) void k_scan_block(const int* __restrict__ deg,
                                                           int* __restrict__ offs,
                                                           int* __restrict__ bsum) {
    __shared__ int ts[SCAN_BLOCK];
    const int base = blockIdx.x * SCAN_CHUNK + threadIdx.x * SCAN_ITEMS;
    int v[SCAN_ITEMS];
    int s = 0;
#pragma unroll
    for (int k = 0; k < SCAN_ITEMS; ++k) {
        int idx = base + k;
        v[k] = (idx < N_NODES) ? deg[idx] : 0;
        s += v[k];
    }
    ts[threadIdx.x] = s;
    __syncthreads();
    // Hillis-Steele inclusive scan over thread sums
    for (int d = 1; d < SCAN_BLOCK; d <<= 1) {
        int t = (threadIdx.x >= d) ? ts[threadIdx.x - d] : 0;
        __syncthreads();
        ts[threadIdx.x] += t;
        __syncthreads();
    }
    int run = ts[threadIdx.x] - s;  // thread-exclusive prefix
#pragma unroll
    for (int k = 0; k < SCAN_ITEMS; ++k) {
        int idx = base + k;
        if (idx < N_NODES) offs[idx] = run;
        run += v[k];
    }
    if (threadIdx.x == SCAN_BLOCK - 1) bsum[blockIdx.x] = ts[SCAN_BLOCK - 1];
}

// serial exclusive scan of the 49 block totals (trivial size)
__global__ void k_scan_sums(int* __restrict__ bsum, int nb) {
    if (blockIdx.x == 0 && threadIdx.x == 0) {
        int run = 0;
        for (int i = 0; i < nb; ++i) { int v = bsum[i]; bsum[i] = run; run += v; }
    }
}

// offs += block offset; cursor = offs; ideg = 1/max(deg,1)
__global__ void k_finalize(const int* __restrict__ deg, int* __restrict__ offs,
                           const int* __restrict__ bsum, int* __restrict__ cursor,
                           float* __restrict__ ideg, int n) {
    int i = blockIdx.x * 256 + threadIdx.x;
    if (i >= n) return;
    int o = offs[i] + bsum[i >> 11];  // 2048-element chunks
    offs[i] = o;
    cursor[i] = o;
    ideg[i] = 1.0f / fmaxf((float)deg[i], 1.0f);
}

// scatter edges into CSR buckets
__global__ void k_bucket(const int* __restrict__ ei, int* __restrict__ cursor,
                         int* __restrict__ nbr, int E) {
    int e = blockIdx.x * 256 + threadIdx.x;
    if (e >= E) return;
    int dst = ei[N_EDGES + e];
    int pos = atomicAdd(&cursor[dst], 1);
    nbr[pos] = ei[e];
}

// Gather aggregation: one wave per node; lane owns 2 channels (float2).
// agg[node] = mean of x[nbr] rows (ideg folded in). No atomics, no memset.
// offs/deg are wave-uniform -> readfirstlane so nbr indices become s_loads.
__global__ __launch_bounds__(256) void k_gather(const float* __restrict__ x,
                                                const int* __restrict__ offs,
                                                const int* __restrict__ deg,
                                                const float* __restrict__ ideg,
                                                const int* __restrict__ nbr,
                                                float* __restrict__ agg, int n) {
    int node = blockIdx.x * 4 + (threadIdx.x >> 6);
    if (node >= n) return;
    int lane = threadIdx.x & 63;
    int off = __builtin_amdgcn_readfirstlane(offs[node]);
    int d   = __builtin_amdgcn_readfirstlane(deg[node]);
    float a0 = 0.f, a1 = 0.f;
    int j = 0;
    for (; j + 8 <= d; j += 8) {  // 8 independent row-loads in flight
        int s[8];
#pragma unroll
        for (int u = 0; u < 8; ++u) s[u] = nbr[off + j + u];
        float2 v[8];
#pragma unroll
        for (int u = 0; u < 8; ++u)
            v[u] = *reinterpret_cast<const float2*>(x + (size_t)s[u] * HID + lane * 2);
#pragma unroll
        for (int u = 0; u < 8; ++u) { a0 += v[u].x; a1 += v[u].y; }
    }
    for (; j < d; ++j) {
        int s = nbr[off + j];
        float2 v = *reinterpret_cast<const float2*>(x + (size_t)s * HID + lane * 2);
        a0 += v.x; a1 += v.y;
    }
    float sc = ideg[node];
    float2 o; o.x = a0 * sc; o.y = a1 * sc;
    *reinterpret_cast<float2*>(agg + (size_t)node * HID + lane * 2) = o;
}

// Transpose 7 [128][128] matrices into WT: [0..2]=Wl, [3..5]=Wr, [6]=Wlin1
__global__ void k_transpose(const float* __restrict__ Wl, const float* __restrict__ Wr,
                            const float* __restrict__ Wlin1, float* __restrict__ WT) {
    int t = blockIdx.x * 256 + threadIdx.x;
    if (t >= 7 * 16384) return;
    int m = t >> 14;
    int idx = t & 16383;
    int r = idx >> 7, c = idx & 127;
    const float* src = (m < 3) ? (Wl + m * 16384)
                     : (m < 6) ? (Wr + (m - 3) * 16384)
                               : Wlin1;
    WT[(size_t)m * 16384 + c * 128 + r] = src[idx];
}

// SAGE layer: out = agg @ WlT + x @ WrT + bl; L2-normalize rows; relu.
// Block: 256 threads, 64 rows. Thread (ty=t>>4, tx=t&15) owns 4 rows x 8 cols.
// LDS 67.5 KB -> 2 blocks/CU (2 waves/SIMD) — flagged for occupancy check.
__global__ __launch_bounds__(256) void k_sage(const float* __restrict__ xin,
                                              const float* __restrict__ agg,
                                              const float* __restrict__ WlT,
                                              const float* __restrict__ WrT,
                                              const float* __restrict__ bl,
                                              float* __restrict__ xout, int n) {
    // pad 132: rows stay float4-aligned; k-loop row stride 4*132 words ≡ 16
    // mod 32 banks -> 2-way aliasing only (free per m136).
    __shared__ __align__(16) float As[64][132];
    __shared__ __align__(16) float Xs[64][132];
    const int t = threadIdx.x;
    const int row0 = blockIdx.x * 64;

#pragma unroll
    for (int rr = 0; rr < 8; ++rr) {
        int r = (t >> 5) + rr * 8;
        int c = (t & 31) * 4;
        int gr = row0 + r;
        float4 va = {0.f, 0.f, 0.f, 0.f}, vx = {0.f, 0.f, 0.f, 0.f};
        if (gr < n) {
            va = *reinterpret_cast<const float4*>(agg + (size_t)gr * HID + c);
            vx = *reinterpret_cast<const float4*>(xin + (size_t)gr * HID + c);
        }
        *reinterpret_cast<float4*>(&As[r][c]) = va;
        *reinterpret_cast<float4*>(&Xs[r][c]) = vx;
    }
    __syncthreads();

    const int tx = t & 15, ty = t >> 4;
    const float* wlp = WlT + tx * 8;
    const float* wrp = WrT + tx * 8;

    float acc[4][8];
#pragma unroll
    for (int j = 0; j < 8; ++j) {
        float b = bl[tx * 8 + j];
#pragma unroll
        for (int i = 0; i < 4; ++i) acc[i][j] = b;
    }

#pragma unroll 4
    for (int k = 0; k < 128; ++k) {
        float av[4], xv[4];
#pragma unroll
        for (int i = 0; i < 4; ++i) {
            av[i] = As[ty * 4 + i][k];
            xv[i] = Xs[ty * 4 + i][k];
        }
        float4 wl0 = *reinterpret_cast<const float4*>(wlp + k * 128);
        float4 wl1 = *reinterpret_cast<const float4*>(wlp + k * 128 + 4);
        float4 wr0 = *reinterpret_cast<const float4*>(wrp + k * 128);
        float4 wr1 = *reinterpret_cast<const float4*>(wrp + k * 128 + 4);
        float wa[8] = {wl0.x, wl0.y, wl0.z, wl0.w, wl1.x, wl1.y, wl1.z, wl1.w};
        float wb[8] = {wr0.x, wr0.y, wr0.z, wr0.w, wr1.x, wr1.y, wr1.z, wr1.w};
#pragma unroll
        for (int i = 0; i < 4; ++i)
#pragma unroll
            for (int j = 0; j < 8; ++j)
                acc[i][j] += av[i] * wa[j] + xv[i] * wb[j];
    }

#pragma unroll
    for (int i = 0; i < 4; ++i) {
        float ss = 0.f;
#pragma unroll
        for (int j = 0; j < 8; ++j) ss += acc[i][j] * acc[i][j];
#pragma unroll
        for (int m = 1; m < 16; m <<= 1) ss += __shfl_xor(ss, m, 64);
        float inv = 1.0f / fmaxf(sqrtf(ss), EPS);
        int gr = row0 + ty * 4 + i;
        if (gr < n) {
            float4 o0, o1;
            o0.x = fmaxf(acc[i][0] * inv, 0.f);
            o0.y = fmaxf(acc[i][1] * inv, 0.f);
            o0.z = fmaxf(acc[i][2] * inv, 0.f);
            o0.w = fmaxf(acc[i][3] * inv, 0.f);
            o1.x = fmaxf(acc[i][4] * inv, 0.f);
            o1.y = fmaxf(acc[i][5] * inv, 0.f);
            o1.z = fmaxf(acc[i][6] * inv, 0.f);
            o1.w = fmaxf(acc[i][7] * inv, 0.f);
            *reinterpret_cast<float4*>(xout + (size_t)gr * HID + tx * 8) = o0;
            *reinterpret_cast<float4*>(xout + (size_t)gr * HID + tx * 8 + 4) = o1;
        }
    }
}

// Final MLP: h = relu(x @ W1T + b1); out = h @ W2.T + b2 (fused).
__global__ __launch_bounds__(256) void k_final(const float* __restrict__ xin,
                                               const float* __restrict__ W1T,
                                               const float* __restrict__ b1,
                                               const float* __restrict__ W2,
                                               const float* __restrict__ b2,
                                               float* __restrict__ out, int n) {
    __shared__ __align__(16) float Xs[64][132];
    const int t = threadIdx.x;
    const int row0 = blockIdx.x * 64;

#pragma unroll
    for (int rr = 0; rr < 8; ++rr) {
        int r = (t >> 5) + rr * 8;
        int c = (t & 31) * 4;
        int gr = row0 + r;
        float4 vx = {0.f, 0.f, 0.f, 0.f};
        if (gr < n) vx = *reinterpret_cast<const float4*>(xin + (size_t)gr * HID + c);
        *reinterpret_cast<float4*>(&Xs[r][c]) = vx;
    }
    __syncthreads();

    const int tx = t & 15, ty = t >> 4;
    const float* wp = W1T + tx * 8;

    float acc[4][8];
#pragma unroll
    for (int j = 0; j < 8; ++j) {
        float b = b1[tx * 8 + j];
#pragma unroll
        for (int i = 0; i < 4; ++i) acc[i][j] = b;
    }

#pragma unroll 4
    for (int k = 0; k < 128; ++k) {
        float xv[4];
#pragma unroll
        for (int i = 0; i < 4; ++i) xv[i] = Xs[ty * 4 + i][k];
        float4 w0 = *reinterpret_cast<const float4*>(wp + k * 128);
        float4 w1 = *reinterpret_cast<const float4*>(wp + k * 128 + 4);
        float wa[8] = {w0.x, w0.y, w0.z, w0.w, w1.x, w1.y, w1.z, w1.w};
#pragma unroll
        for (int i = 0; i < 4; ++i)
#pragma unroll
            for (int j = 0; j < 8; ++j) acc[i][j] += xv[i] * wa[j];
    }

    // out = relu(acc) @ W2.T + b2, reduce partials across the 16 tx lanes
#pragma unroll
    for (int i = 0; i < 4; ++i) {
        float p0 = 0.f, p1 = 0.f;
#pragma unroll
        for (int j = 0; j < 8; ++j) {
            float h = fmaxf(acc[i][j], 0.f);
            p0 += h * W2[tx * 8 + j];
            p1 += h * W2[128 + tx * 8 + j];
        }
#pragma unroll
        for (int m = 1; m < 16; m <<= 1) {
            p0 += __shfl_xor(p0, m, 64);
            p1 += __shfl_xor(p1, m, 64);
        }
        int gr = row0 + ty * 4 + i;
        if (tx == 0 && gr < n) {
            out[(size_t)gr * 2 + 0] = p0 + b2[0];
            out[(size_t)gr * 2 + 1] = p1 + b2[1];
        }
    }
}

extern "C" void kernel_launch(void* const* d_in, const int* in_sizes, int n_in,
                              void* d_out, int out_size, void* d_ws, size_t ws_size,
                              hipStream_t stream) {
    const float* x     = (const float*)d_in[0];
    const int*   ei    = (const int*)  d_in[1];
    const float* Wl    = (const float*)d_in[2];
    const float* bl    = (const float*)d_in[3];
    const float* Wr    = (const float*)d_in[4];
    const float* Wlin1 = (const float*)d_in[5];
    const float* blin1 = (const float*)d_in[6];
    const float* Wlin2 = (const float*)d_in[7];
    const float* blin2 = (const float*)d_in[8];
    float* out = (float*)d_out;

    // workspace layout (~111 MB total):
    // floats: xbuf[N*128] | agg[N*128] | ideg[N] | WT[7*16384]
    // ints:   deg[N] | offs[N] | cursor[N] | bsum[64] | nbr[E]
    float* xbuf = (float*)d_ws;
    float* agg  = xbuf + (size_t)N_NODES * HID;
    float* ideg = agg  + (size_t)N_NODES * HID;
    float* WT   = ideg + N_NODES;
    int* deg    = (int*)(WT + 7 * 16384);
    int* offs   = deg + N_NODES;
    int* cursor = offs + N_NODES;
    int* bsum   = cursor + N_NODES;
    int* nbr    = bsum + 64;

    // ---- CSR build (once per call) ----
    hipMemsetAsync(deg, 0, N_NODES * sizeof(int), stream);
    k_deg<<<(N_EDGES + 255) / 256, 256, 0, stream>>>(ei + N_EDGES, deg, N_EDGES);
    k_scan_block<<<SCAN_NBLOCKS, SCAN_BLOCK, 0, stream>>>(deg, offs, bsum);
    k_scan_sums<<<1, 64, 0, stream>>>(bsum, SCAN_NBLOCKS);
    k_finalize<<<(N_NODES + 255) / 256, 256, 0, stream>>>(deg, offs, bsum, cursor,
                                                          ideg, N_NODES);
    k_bucket<<<(N_EDGES + 255) / 256, 256, 0, stream>>>(ei, cursor, nbr, N_EDGES);
    k_transpose<<<(7 * 16384 + 255) / 256, 256, 0, stream>>>(Wl, Wr, Wlin1, WT);

    // ---- layers ----
    const int sage_grid = (N_NODES + 63) / 64;
    const int gather_grid = (N_NODES + 3) / 4;
    for (int l = 0; l < N_GNN; ++l) {
        const float* xin = (l == 0) ? x : xbuf;
        k_gather<<<gather_grid, 256, 0, stream>>>(xin, offs, deg, ideg, nbr, agg,
                                                  N_NODES);
        k_sage<<<sage_grid, 256, 0, stream>>>(xin, agg,
                                              WT + (size_t)l * 16384,
                                              WT + (size_t)(3 + l) * 16384,
                                              bl + (size_t)l * HID, xbuf, N_NODES);
    }
    k_final<<<sage_grid, 256, 0, stream>>>(xbuf, WT + (size_t)6 * 16384, blin1,
                                           Wlin2, blin2, out, N_NODES);
}

// Round 8
// 849.429 us; speedup vs baseline: 1.2839x; 1.2839x over previous
//
#include <hip/hip_runtime.h>

#define N_NODES 100000
#define N_EDGES 1600000
#define HID 128
#define N_GNN 3
#define OUT_CH 2
#define EPS 1e-12f

#define SCAN_BLOCK 256
#define SCAN_ITEMS 8
#define SCAN_CHUNK 2048
#define SCAN_NBLOCKS ((N_NODES + SCAN_CHUNK - 1) / SCAN_CHUNK)  // 49

typedef __attribute__((ext_vector_type(8))) short short8;
typedef __attribute__((ext_vector_type(4))) float f32x4;

// ---------------------------------------------------------------------------
__global__ void k_deg(const int* __restrict__ dst, int* __restrict__ deg, int E) {
    int i = blockIdx.x * blockDim.x + threadIdx.x;
    if (i < E) atomicAdd(&deg[dst[i]], 1);
}

__global__ __launch_bounds__(SCAN_BLOCK) void k_scan_block(const int* __restrict__ deg,
                                                           int* __restrict__ offs,
                                                           int* __restrict__ bsum) {
    __shared__ int ts[SCAN_BLOCK];
    const int base = blockIdx.x * SCAN_CHUNK + threadIdx.x * SCAN_ITEMS;
    int v[SCAN_ITEMS];
    int s = 0;
#pragma unroll
    for (int k = 0; k < SCAN_ITEMS; ++k) {
        int idx = base + k;
        v[k] = (idx < N_NODES) ? deg[idx] : 0;
        s += v[k];
    }
    ts[threadIdx.x] = s;
    __syncthreads();
    for (int d = 1; d < SCAN_BLOCK; d <<= 1) {
        int t = (threadIdx.x >= d) ? ts[threadIdx.x - d] : 0;
        __syncthreads();
        ts[threadIdx.x] += t;
        __syncthreads();
    }
    int run = ts[threadIdx.x] - s;
#pragma unroll
    for (int k = 0; k < SCAN_ITEMS; ++k) {
        int idx = base + k;
        if (idx < N_NODES) offs[idx] = run;
        run += v[k];
    }
    if (threadIdx.x == SCAN_BLOCK - 1) bsum[blockIdx.x] = ts[SCAN_BLOCK - 1];
}

__global__ void k_scan_sums(int* __restrict__ bsum, int nb) {
    if (blockIdx.x == 0 && threadIdx.x == 0) {
        int run = 0;
        for (int i = 0; i < nb; ++i) { int v = bsum[i]; bsum[i] = run; run += v; }
    }
}

__global__ void k_finalize(const int* __restrict__ deg, int* __restrict__ offs,
                           const int* __restrict__ bsum, int* __restrict__ cursor,
                           float* __restrict__ ideg, int n) {
    int i = blockIdx.x * 256 + threadIdx.x;
    if (i >= n) return;
    int o = offs[i] + bsum[i >> 11];
    offs[i] = o;
    cursor[i] = o;
    ideg[i] = 1.0f / fmaxf((float)deg[i], 1.0f);
}

__global__ void k_bucket(const int* __restrict__ ei, int* __restrict__ cursor,
                         int* __restrict__ nbr, int E) {
    int e = blockIdx.x * 256 + threadIdx.x;
    if (e >= E) return;
    int dst = ei[N_EDGES + e];
    int pos = atomicAdd(&cursor[dst], 1);
    nbr[pos] = ei[e];
}

// Gather: half-wave (32 lanes) per node, float4/lane covers a 512B row in one
// instruction; 2 nodes per wave halves issued-instruction count vs round-6.
__global__ __launch_bounds__(256) void k_gather(const float* __restrict__ x,
                                                const int* __restrict__ offs,
                                                const int* __restrict__ deg,
                                                const float* __restrict__ ideg,
                                                const int* __restrict__ nbr,
                                                float* __restrict__ agg, int n) {
    int node = blockIdx.x * 8 + (threadIdx.x >> 5);
    if (node >= n) return;
    int lane = threadIdx.x & 31;
    int off = offs[node], d = deg[node];
    f32x4 a = {0.f, 0.f, 0.f, 0.f};
    int j = 0;
    for (; j + 8 <= d; j += 8) {  // 8 independent row-loads in flight
        int s[8];
#pragma unroll
        for (int u = 0; u < 8; ++u) s[u] = nbr[off + j + u];
#pragma unroll
        for (int u = 0; u < 8; ++u)
            a += *reinterpret_cast<const f32x4*>(x + (size_t)s[u] * HID + lane * 4);
    }
    for (; j < d; ++j) {
        int s = nbr[off + j];
        a += *reinterpret_cast<const f32x4*>(x + (size_t)s * HID + lane * 4);
    }
    f32x4 o = a * ideg[node];
    *reinterpret_cast<f32x4*>(agg + (size_t)node * HID + lane * 4) = o;
}

// ---------------------------------------------------------------------------
// Pack 7 weight matrices ([0..2]=Wl, [3..5]=Wr, [6]=Wlin1) into MFMA B-frag
// order, split into bf16 hi/lo (truncation split; err ~2^-16 with 3-term MFMA).
// B[k][c] = W[c][k] (for out = A @ W.T). Frag idx: (((m*8+nt)*4+ks)*64+l)*8+j
// where lane l supplies col c = nt*16+(l&15), k = ks*32+(l>>4)*8+j.
// (A and B use the same (lane,j)->k convention, so any common hardware
//  k-permutation cancels — only row=l&15 / col=l&15 must be right.)
__global__ void k_makefrags(const float* __restrict__ Wl, const float* __restrict__ Wr,
                            const float* __restrict__ Wlin1,
                            unsigned short* __restrict__ fhi,
                            unsigned short* __restrict__ flo) {
    int t = blockIdx.x * 256 + threadIdx.x;
    if (t >= 7 * 16384) return;
    int j  = t & 7;
    int l  = (t >> 3) & 63;
    int ks = (t >> 9) & 3;
    int nt = (t >> 11) & 7;
    int m  = t >> 14;
    int c = nt * 16 + (l & 15);
    int k = ks * 32 + ((l >> 4) & 3) * 8 + j;
    const float* src = (m < 3) ? (Wl + m * 16384)
                     : (m < 6) ? (Wr + (m - 3) * 16384)
                               : Wlin1;
    float a = src[c * 128 + k];
    unsigned u  = __float_as_uint(a);
    unsigned uh = u & 0xffff0000u;
    float r = a - __uint_as_float(uh);
    fhi[t] = (unsigned short)(uh >> 16);
    flo[t] = (unsigned short)(__float_as_uint(r) >> 16);
}

__device__ __forceinline__ void split8(const f32x4 a0, const f32x4 a1,
                                       short8& h, short8& l) {
    float a[8] = {a0[0], a0[1], a0[2], a0[3], a1[0], a1[1], a1[2], a1[3]};
#pragma unroll
    for (int j = 0; j < 8; ++j) {
        unsigned u  = __float_as_uint(a[j]);
        unsigned uh = u & 0xffff0000u;
        h[j] = (short)(uh >> 16);
        float r = a[j] - __uint_as_float(uh);
        l[j] = (short)(__float_as_uint(r) >> 16);
    }
}

// SAGE layer via MFMA 16x16x32 bf16, 3-term hi/lo split, no LDS.
// Wave owns 16 rows x 128 cols: acc[8] 16x16 tiles; A loaded from global
// (lane: row l&15, k=(l>>4)*8+j), B-frags precomputed. 6 MFMA per (nt,ks).
// Epilogue: +bias (init), row L2-norm via 16-lane shfl_xor, relu, store.
__global__ __launch_bounds__(256) void k_sage_mfma(
    const float* __restrict__ xin, const float* __restrict__ agg,
    const unsigned short* __restrict__ fhi, const unsigned short* __restrict__ flo,
    int lmat, const float* __restrict__ bl, float* __restrict__ xout, int n) {
    const int l  = threadIdx.x & 63;
    const int lr = l & 15, lk = l >> 4;
    const int row0 = blockIdx.x * 64 + (threadIdx.x >> 6) * 16;
    const int gr = row0 + lr;           // A-row this lane supplies
    const bool rok = gr < n;

    f32x4 acc[8];
#pragma unroll
    for (int nt = 0; nt < 8; ++nt) {    // C col = nt*16+lr: bias same for all 4 rows
        float b = bl[nt * 16 + lr];
        f32x4 t = {b, b, b, b};
        acc[nt] = t;
    }

    const size_t abase = (size_t)gr * HID + lk * 8;
#pragma unroll
    for (int ks = 0; ks < 4; ++ks) {
        f32x4 a0 = {0.f,0.f,0.f,0.f}, a1 = a0, x0 = a0, x1 = a0;
        if (rok) {
            const f32x4* ap = reinterpret_cast<const f32x4*>(agg + abase + ks * 32);
            const f32x4* xp = reinterpret_cast<const f32x4*>(xin + abase + ks * 32);
            a0 = ap[0]; a1 = ap[1];
            x0 = xp[0]; x1 = xp[1];
        }
        short8 ah, al, xh, xl;
        split8(a0, a1, ah, al);
        split8(x0, x1, xh, xl);

        const int foL = ((lmat * 8) * 4 + ks) * 512 + l * 8;
        const int foR = (((3 + lmat) * 8) * 4 + ks) * 512 + l * 8;
#pragma unroll
        for (int nt = 0; nt < 8; ++nt) {
            short8 blh = *reinterpret_cast<const short8*>(fhi + foL + nt * 2048);
            short8 bll = *reinterpret_cast<const short8*>(flo + foL + nt * 2048);
            short8 brh = *reinterpret_cast<const short8*>(fhi + foR + nt * 2048);
            short8 brl = *reinterpret_cast<const short8*>(flo + foR + nt * 2048);
            acc[nt] = __builtin_amdgcn_mfma_f32_16x16x32_bf16(ah, blh, acc[nt], 0, 0, 0);
            acc[nt] = __builtin_amdgcn_mfma_f32_16x16x32_bf16(al, blh, acc[nt], 0, 0, 0);
            acc[nt] = __builtin_amdgcn_mfma_f32_16x16x32_bf16(ah, bll, acc[nt], 0, 0, 0);
            acc[nt] = __builtin_amdgcn_mfma_f32_16x16x32_bf16(xh, brh, acc[nt], 0, 0, 0);
            acc[nt] = __builtin_amdgcn_mfma_f32_16x16x32_bf16(xl, brh, acc[nt], 0, 0, 0);
            acc[nt] = __builtin_amdgcn_mfma_f32_16x16x32_bf16(xh, brl, acc[nt], 0, 0, 0);
        }
    }

    // C/D: lane holds cols nt*16+lr of rows row0 + lk*4 + i
#pragma unroll
    for (int i = 0; i < 4; ++i) {
        float v[8];
        float ss = 0.f;
#pragma unroll
        for (int nt = 0; nt < 8; ++nt) { v[nt] = acc[nt][i]; ss += v[nt] * v[nt]; }
#pragma unroll
        for (int m = 1; m < 16; m <<= 1) ss += __shfl_xor(ss, m, 64);
        float inv = 1.0f / fmaxf(sqrtf(ss), EPS);
        int orow = row0 + lk * 4 + i;
        if (orow < n) {
#pragma unroll
            for (int nt = 0; nt < 8; ++nt)
                xout[(size_t)orow * HID + nt * 16 + lr] = fmaxf(v[nt] * inv, 0.f);
        }
    }
}

// Final MLP: h = relu(x @ Wlin1.T + b1) via MFMA (mat 6), then 2-col output
// via per-lane partials + 16-lane shfl reduce.
__global__ __launch_bounds__(256) void k_final_mfma(
    const float* __restrict__ xin,
    const unsigned short* __restrict__ fhi, const unsigned short* __restrict__ flo,
    const float* __restrict__ b1, const float* __restrict__ W2,
    const float* __restrict__ b2, float* __restrict__ out, int n) {
    const int l  = threadIdx.x & 63;
    const int lr = l & 15, lk = l >> 4;
    const int row0 = blockIdx.x * 64 + (threadIdx.x >> 6) * 16;
    const int gr = row0 + lr;
    const bool rok = gr < n;

    f32x4 acc[8];
#pragma unroll
    for (int nt = 0; nt < 8; ++nt) {
        float b = b1[nt * 16 + lr];
        f32x4 t = {b, b, b, b};
        acc[nt] = t;
    }

    const size_t abase = (size_t)gr * HID + lk * 8;
#pragma unroll
    for (int ks = 0; ks < 4; ++ks) {
        f32x4 x0 = {0.f,0.f,0.f,0.f}, x1 = x0;
        if (rok) {
            const f32x4* xp = reinterpret_cast<const f32x4*>(xin + abase + ks * 32);
            x0 = xp[0]; x1 = xp[1];
        }
        short8 xh, xl;
        split8(x0, x1, xh, xl);
        const int fo = ((6 * 8) * 4 + ks) * 512 + l * 8;
#pragma unroll
        for (int nt = 0; nt < 8; ++nt) {
            short8 bh = *reinterpret_cast<const short8*>(fhi + fo + nt * 2048);
            short8 blo = *reinterpret_cast<const short8*>(flo + fo + nt * 2048);
            acc[nt] = __builtin_amdgcn_mfma_f32_16x16x32_bf16(xh, bh, acc[nt], 0, 0, 0);
            acc[nt] = __builtin_amdgcn_mfma_f32_16x16x32_bf16(xl, bh, acc[nt], 0, 0, 0);
            acc[nt] = __builtin_amdgcn_mfma_f32_16x16x32_bf16(xh, blo, acc[nt], 0, 0, 0);
        }
    }

    float w20[8], w21[8];
#pragma unroll
    for (int nt = 0; nt < 8; ++nt) {
        w20[nt] = W2[nt * 16 + lr];
        w21[nt] = W2[HID + nt * 16 + lr];
    }
#pragma unroll
    for (int i = 0; i < 4; ++i) {
        float p0 = 0.f, p1 = 0.f;
#pragma unroll
        for (int nt = 0; nt < 8; ++nt) {
            float h = fmaxf(acc[nt][i], 0.f);
            p0 += h * w20[nt];
            p1 += h * w21[nt];
        }
#pragma unroll
        for (int m = 1; m < 16; m <<= 1) {
            p0 += __shfl_xor(p0, m, 64);
            p1 += __shfl_xor(p1, m, 64);
        }
        int orow = row0 + lk * 4 + i;
        if (lr == 0 && orow < n) {
            out[(size_t)orow * 2 + 0] = p0 + b2[0];
            out[(size_t)orow * 2 + 1] = p1 + b2[1];
        }
    }
}

extern "C" void kernel_launch(void* const* d_in, const int* in_sizes, int n_in,
                              void* d_out, int out_size, void* d_ws, size_t ws_size,
                              hipStream_t stream) {
    const float* x     = (const float*)d_in[0];
    const int*   ei    = (const int*)  d_in[1];
    const float* Wl    = (const float*)d_in[2];
    const float* bl    = (const float*)d_in[3];
    const float* Wr    = (const float*)d_in[4];
    const float* Wlin1 = (const float*)d_in[5];
    const float* blin1 = (const float*)d_in[6];
    const float* Wlin2 = (const float*)d_in[7];
    const float* blin2 = (const float*)d_in[8];
    float* out = (float*)d_out;

    // workspace: xbuf[N*128] | agg[N*128] | ideg[N] | fhi[7*16384] u16 |
    //            flo[7*16384] u16 | deg[N] | offs[N] | cursor[N] | bsum[64] | nbr[E]
    float* xbuf = (float*)d_ws;
    float* agg  = xbuf + (size_t)N_NODES * HID;
    float* ideg = agg  + (size_t)N_NODES * HID;
    unsigned short* fhi = (unsigned short*)(ideg + N_NODES);
    unsigned short* flo = fhi + 7 * 16384;
    int* deg    = (int*)(flo + 7 * 16384);
    int* offs   = deg + N_NODES;
    int* cursor = offs + N_NODES;
    int* bsum   = cursor + N_NODES;
    int* nbr    = bsum + 64;

    // ---- CSR build + weight frag pack (once per call) ----
    hipMemsetAsync(deg, 0, N_NODES * sizeof(int), stream);
    k_deg<<<(N_EDGES + 255) / 256, 256, 0, stream>>>(ei + N_EDGES, deg, N_EDGES);
    k_scan_block<<<SCAN_NBLOCKS, SCAN_BLOCK, 0, stream>>>(deg, offs, bsum);
    k_scan_sums<<<1, 64, 0, stream>>>(bsum, SCAN_NBLOCKS);
    k_finalize<<<(N_NODES + 255) / 256, 256, 0, stream>>>(deg, offs, bsum, cursor,
                                                          ideg, N_NODES);
    k_bucket<<<(N_EDGES + 255) / 256, 256, 0, stream>>>(ei, cursor, nbr, N_EDGES);
    k_makefrags<<<(7 * 16384 + 255) / 256, 256, 0, stream>>>(Wl, Wr, Wlin1, fhi, flo);

    // ---- layers ----
    const int mm_grid = (N_NODES + 63) / 64;       // 1563
    const int gather_grid = (N_NODES + 7) / 8;     // 12500
    for (int l = 0; l < N_GNN; ++l) {
        const float* xin = (l == 0) ? x : xbuf;
        k_gather<<<gather_grid, 256, 0, stream>>>(xin, offs, deg, ideg, nbr, agg,
                                                  N_NODES);
        k_sage_mfma<<<mm_grid, 256, 0, stream>>>(xin, agg, fhi, flo, l,
                                                 bl + (size_t)l * HID, xbuf, N_NODES);
    }
    k_final_mfma<<<mm_grid, 256, 0, stream>>>(xbuf, fhi, flo, blin1, Wlin2, blin2,
                                              out, N_NODES);
}

// Round 10
// 719.637 us; speedup vs baseline: 1.5155x; 1.1804x over previous
//
#include <hip/hip_runtime.h>

#define N_NODES 100000
#define N_EDGES 1600000
#define HID 128
#define N_GNN 3
#define OUT_CH 2
#define EPS 1e-12f

#define NPB 256                                   // nodes per bucket
#define NBUCK ((N_NODES + NPB - 1) / NPB)         // 391
#define EPB 4096                                  // edges per block (hist/part)
#define EBLOCKS ((N_EDGES + EPB - 1) / EPB)       // 391

typedef __attribute__((ext_vector_type(8))) short short8;
typedef __attribute__((ext_vector_type(4))) float f32x4;

// ---------------------------------------------------------------------------
// Stage A: per-bucket edge histogram (bucket = dst>>8). LDS-aggregated.
__global__ __launch_bounds__(256) void k_hist(const int* __restrict__ dst,
                                              int* __restrict__ bcnt, int E) {
    __shared__ int h[NBUCK];
    for (int i = threadIdx.x; i < NBUCK; i += 256) h[i] = 0;
    __syncthreads();
    int e0 = blockIdx.x * EPB;
    int e1 = e0 + EPB < E ? e0 + EPB : E;
    for (int e = e0 + threadIdx.x; e < e1; e += 256)
        atomicAdd(&h[dst[e] >> 8], 1);
    __syncthreads();
    for (int i = threadIdx.x; i < NBUCK; i += 256) {
        int v = h[i];
        if (v) atomicAdd(&bcnt[i], v);
    }
}

// Stage B: serial exclusive scan of 391 bucket counts; init cursors.
__global__ void k_bscan(const int* __restrict__ bcnt, int* __restrict__ boffs,
                        int* __restrict__ gcur) {
    if (blockIdx.x == 0 && threadIdx.x == 0) {
        int run = 0;
        for (int i = 0; i < NBUCK; ++i) {
            boffs[i] = run;
            gcur[i] = run;
            run += bcnt[i];
        }
        boffs[NBUCK] = run;
    }
}

// Stage C: partition edges into bucket regions, block-aggregated cursors.
// Entry: (dst&255)<<24 | src  (src<2^17 fits). Writes cluster at ~391
// frontier lines -> line reuse, unlike the old full-random scatter.
__global__ __launch_bounds__(256) void k_part(const int* __restrict__ ei,
                                              int* __restrict__ gcur,
                                              unsigned* __restrict__ part, int E) {
    __shared__ int h[NBUCK], base[NBUCK];
    for (int i = threadIdx.x; i < NBUCK; i += 256) h[i] = 0;
    __syncthreads();
    int e0 = blockIdx.x * EPB;
    int e1 = e0 + EPB < E ? e0 + EPB : E;
    for (int e = e0 + threadIdx.x; e < e1; e += 256)
        atomicAdd(&h[ei[N_EDGES + e] >> 8], 1);
    __syncthreads();
    for (int i = threadIdx.x; i < NBUCK; i += 256) {
        int v = h[i];
        base[i] = v ? atomicAdd(&gcur[i], v) : 0;
        h[i] = 0;
    }
    __syncthreads();
    for (int e = e0 + threadIdx.x; e < e1; e += 256) {
        int d = ei[N_EDGES + e], s = ei[e];
        int b = d >> 8;
        int p = base[b] + atomicAdd(&h[b], 1);
        part[p] = ((unsigned)(d & 255) << 24) | (unsigned)s;
    }
}

// Stage D: one block per bucket. Count -> scan -> emit deg/offs/ideg ->
// scatter nbr confined to this bucket's contiguous region (~16KB, L2-local).
__global__ __launch_bounds__(256) void k_csr(const unsigned* __restrict__ part,
                                             const int* __restrict__ boffs,
                                             int* __restrict__ deg,
                                             int* __restrict__ offs,
                                             float* __restrict__ ideg,
                                             int* __restrict__ nbr, int n) {
    __shared__ int d[NPB], sc[NPB], cur[NPB];
    const int tid = threadIdx.x;
    const int node0 = blockIdx.x << 8;
    const int p0 = boffs[blockIdx.x], p1 = boffs[blockIdx.x + 1];
    d[tid] = 0;
    __syncthreads();
    for (int p = p0 + tid; p < p1; p += 256)
        atomicAdd(&d[part[p] >> 24], 1);
    __syncthreads();
    int v = d[tid];
    sc[tid] = v;
    __syncthreads();
    for (int o = 1; o < NPB; o <<= 1) {
        int t = (tid >= o) ? sc[tid - o] : 0;
        __syncthreads();
        sc[tid] += t;
        __syncthreads();
    }
    int excl = sc[tid] - v;
    int node = node0 + tid;
    if (node < n) {
        offs[node] = p0 + excl;
        deg[node] = v;
        ideg[node] = 1.0f / fmaxf((float)v, 1.0f);
    }
    cur[tid] = excl;
    __syncthreads();
    for (int p = p0 + tid; p < p1; p += 256) {
        unsigned u = part[p];
        int dl = u >> 24;
        int pos = p0 + atomicAdd(&cur[dl], 1);
        nbr[pos] = (int)(u & 0xFFFFFFu);
    }
}

// ---------------------------------------------------------------------------
// Gather: half-wave (32 lanes) per node, float4/lane covers a 512B row.
__global__ __launch_bounds__(256) void k_gather(const float* __restrict__ x,
                                                const int* __restrict__ offs,
                                                const int* __restrict__ deg,
                                                const float* __restrict__ ideg,
                                                const int* __restrict__ nbr,
                                                float* __restrict__ agg, int n) {
    int node = blockIdx.x * 8 + (threadIdx.x >> 5);
    if (node >= n) return;
    int lane = threadIdx.x & 31;
    int off = offs[node], d = deg[node];
    f32x4 a = {0.f, 0.f, 0.f, 0.f};
    int j = 0;
    for (; j + 8 <= d; j += 8) {  // 8 independent row-loads in flight
        int s[8];
#pragma unroll
        for (int u = 0; u < 8; ++u) s[u] = nbr[off + j + u];
#pragma unroll
        for (int u = 0; u < 8; ++u)
            a += *reinterpret_cast<const f32x4*>(x + (size_t)s[u] * HID + lane * 4);
    }
    for (; j < d; ++j) {
        int s = nbr[off + j];
        a += *reinterpret_cast<const f32x4*>(x + (size_t)s * HID + lane * 4);
    }
    f32x4 o = a * ideg[node];
    *reinterpret_cast<f32x4*>(agg + (size_t)node * HID + lane * 4) = o;
}

// ---------------------------------------------------------------------------
// Pack 7 weight matrices ([0..2]=Wl, [3..5]=Wr, [6]=Wlin1) into MFMA B-frag
// order, split into bf16 hi/lo (truncation split; err ~2^-16 with 3-term MFMA).
// B[k][c] = W[c][k]. Frag idx: (((m*8+nt)*4+ks)*64+l)*8+j, lane l supplies
// col c = nt*16+(l&15), k = ks*32+(l>>4)*8+j. A and B share the (lane,j)->k
// convention so any common hardware k-permutation cancels.
__global__ void k_makefrags(const float* __restrict__ Wl, const float* __restrict__ Wr,
                            const float* __restrict__ Wlin1,
                            unsigned short* __restrict__ fhi,
                            unsigned short* __restrict__ flo) {
    int t = blockIdx.x * 256 + threadIdx.x;
    if (t >= 7 * 16384) return;
    int j  = t & 7;
    int l  = (t >> 3) & 63;
    int ks = (t >> 9) & 3;
    int nt = (t >> 11) & 7;
    int m  = t >> 14;
    int c = nt * 16 + (l & 15);
    int k = ks * 32 + ((l >> 4) & 3) * 8 + j;
    const float* src = (m < 3) ? (Wl + m * 16384)
                     : (m < 6) ? (Wr + (m - 3) * 16384)
                               : Wlin1;
    float a = src[c * 128 + k];
    unsigned u  = __float_as_uint(a);
    unsigned uh = u & 0xffff0000u;
    float r = a - __uint_as_float(uh);
    fhi[t] = (unsigned short)(uh >> 16);
    flo[t] = (unsigned short)(__float_as_uint(r) >> 16);
}

__device__ __forceinline__ void split8(const f32x4 a0, const f32x4 a1,
                                       short8& h, short8& l) {
    float a[8] = {a0[0], a0[1], a0[2], a0[3], a1[0], a1[1], a1[2], a1[3]};
#pragma unroll
    for (int j = 0; j < 8; ++j) {
        unsigned u  = __float_as_uint(a[j]);
        unsigned uh = u & 0xffff0000u;
        h[j] = (short)(uh >> 16);
        float r = a[j] - __uint_as_float(uh);
        l[j] = (short)(__float_as_uint(r) >> 16);
    }
}

// SAGE layer via MFMA 16x16x32 bf16, 3-term hi/lo split, no LDS.
__global__ __launch_bounds__(256) void k_sage_mfma(
    const float* __restrict__ xin, const float* __restrict__ agg,
    const unsigned short* __restrict__ fhi, const unsigned short* __restrict__ flo,
    int lmat, const float* __restrict__ bl, float* __restrict__ xout, int n) {
    const int l  = threadIdx.x & 63;
    const int lr = l & 15, lk = l >> 4;
    const int row0 = blockIdx.x * 64 + (threadIdx.x >> 6) * 16;
    const int gr = row0 + lr;           // A-row this lane supplies
    const bool rok = gr < n;

    f32x4 acc[8];
#pragma unroll
    for (int nt = 0; nt < 8; ++nt) {
        float b = bl[nt * 16 + lr];
        f32x4 t = {b, b, b, b};
        acc[nt] = t;
    }

    const size_t abase = (size_t)gr * HID + lk * 8;
#pragma unroll
    for (int ks = 0; ks < 4; ++ks) {
        f32x4 a0 = {0.f,0.f,0.f,0.f}, a1 = a0, x0 = a0, x1 = a0;
        if (rok) {
            const f32x4* ap = reinterpret_cast<const f32x4*>(agg + abase + ks * 32);
            const f32x4* xp = reinterpret_cast<const f32x4*>(xin + abase + ks * 32);
            a0 = ap[0]; a1 = ap[1];
            x0 = xp[0]; x1 = xp[1];
        }
        short8 ah, al, xh, xl;
        split8(a0, a1, ah, al);
        split8(x0, x1, xh, xl);

        const int foL = ((lmat * 8) * 4 + ks) * 512 + l * 8;
        const int foR = (((3 + lmat) * 8) * 4 + ks) * 512 + l * 8;
#pragma unroll
        for (int nt = 0; nt < 8; ++nt) {
            short8 blh = *reinterpret_cast<const short8*>(fhi + foL + nt * 2048);
            short8 bll = *reinterpret_cast<const short8*>(flo + foL + nt * 2048);
            short8 brh = *reinterpret_cast<const short8*>(fhi + foR + nt * 2048);
            short8 brl = *reinterpret_cast<const short8*>(flo + foR + nt * 2048);
            acc[nt] = __builtin_amdgcn_mfma_f32_16x16x32_bf16(ah, blh, acc[nt], 0, 0, 0);
            acc[nt] = __builtin_amdgcn_mfma_f32_16x16x32_bf16(al, blh, acc[nt], 0, 0, 0);
            acc[nt] = __builtin_amdgcn_mfma_f32_16x16x32_bf16(ah, bll, acc[nt], 0, 0, 0);
            acc[nt] = __builtin_amdgcn_mfma_f32_16x16x32_bf16(xh, brh, acc[nt], 0, 0, 0);
            acc[nt] = __builtin_amdgcn_mfma_f32_16x16x32_bf16(xl, brh, acc[nt], 0, 0, 0);
            acc[nt] = __builtin_amdgcn_mfma_f32_16x16x32_bf16(xh, brl, acc[nt], 0, 0, 0);
        }
    }

    // C/D: lane holds cols nt*16+lr of rows row0 + lk*4 + i
#pragma unroll
    for (int i = 0; i < 4; ++i) {
        float v[8];
        float ss = 0.f;
#pragma unroll
        for (int nt = 0; nt < 8; ++nt) { v[nt] = acc[nt][i]; ss += v[nt] * v[nt]; }
#pragma unroll
        for (int m = 1; m < 16; m <<= 1) ss += __shfl_xor(ss, m, 64);
        float inv = 1.0f / fmaxf(sqrtf(ss), EPS);
        int orow = row0 + lk * 4 + i;
        if (orow < n) {
#pragma unroll
            for (int nt = 0; nt < 8; ++nt)
                xout[(size_t)orow * HID + nt * 16 + lr] = fmaxf(v[nt] * inv, 0.f);
        }
    }
}

// Final MLP: h = relu(x @ Wlin1.T + b1) via MFMA (mat 6), then 2-col output.
__global__ __launch_bounds__(256) void k_final_mfma(
    const float* __restrict__ xin,
    const unsigned short* __restrict__ fhi, const unsigned short* __restrict__ flo,
    const float* __restrict__ b1, const float* __restrict__ W2,
    const float* __restrict__ b2, float* __restrict__ out, int n) {
    const int l  = threadIdx.x & 63;
    const int lr = l & 15, lk = l >> 4;
    const int row0 = blockIdx.x * 64 + (threadIdx.x >> 6) * 16;
    const int gr = row0 + lr;
    const bool rok = gr < n;

    f32x4 acc[8];
#pragma unroll
    for (int nt = 0; nt < 8; ++nt) {
        float b = b1[nt * 16 + lr];
        f32x4 t = {b, b, b, b};
        acc[nt] = t;
    }

    const size_t abase = (size_t)gr * HID + lk * 8;
#pragma unroll
    for (int ks = 0; ks < 4; ++ks) {
        f32x4 x0 = {0.f,0.f,0.f,0.f}, x1 = x0;
        if (rok) {
            const f32x4* xp = reinterpret_cast<const f32x4*>(xin + abase + ks * 32);
            x0 = xp[0]; x1 = xp[1];
        }
        short8 xh, xl;
        split8(x0, x1, xh, xl);
        const int fo = ((6 * 8) * 4 + ks) * 512 + l * 8;
#pragma unroll
        for (int nt = 0; nt < 8; ++nt) {
            short8 bh = *reinterpret_cast<const short8*>(fhi + fo + nt * 2048);
            short8 blo = *reinterpret_cast<const short8*>(flo + fo + nt * 2048);
            acc[nt] = __builtin_amdgcn_mfma_f32_16x16x32_bf16(xh, bh, acc[nt], 0, 0, 0);
            acc[nt] = __builtin_amdgcn_mfma_f32_16x16x32_bf16(xl, bh, acc[nt], 0, 0, 0);
            acc[nt] = __builtin_amdgcn_mfma_f32_16x16x32_bf16(xh, blo, acc[nt], 0, 0, 0);
        }
    }

    float w20[8], w21[8];
#pragma unroll
    for (int nt = 0; nt < 8; ++nt) {
        w20[nt] = W2[nt * 16 + lr];
        w21[nt] = W2[HID + nt * 16 + lr];
    }
#pragma unroll
    for (int i = 0; i < 4; ++i) {
        float p0 = 0.f, p1 = 0.f;
#pragma unroll
        for (int nt = 0; nt < 8; ++nt) {
            float h = fmaxf(acc[nt][i], 0.f);
            p0 += h * w20[nt];
            p1 += h * w21[nt];
        }
#pragma unroll
        for (int m = 1; m < 16; m <<= 1) {
            p0 += __shfl_xor(p0, m, 64);
            p1 += __shfl_xor(p1, m, 64);
        }
        int orow = row0 + lk * 4 + i;
        if (lr == 0 && orow < n) {
            out[(size_t)orow * 2 + 0] = p0 + b2[0];
            out[(size_t)orow * 2 + 1] = p1 + b2[1];
        }
    }
}

extern "C" void kernel_launch(void* const* d_in, const int* in_sizes, int n_in,
                              void* d_out, int out_size, void* d_ws, size_t ws_size,
                              hipStream_t stream) {
    const float* x     = (const float*)d_in[0];
    const int*   ei    = (const int*)  d_in[1];
    const float* Wl    = (const float*)d_in[2];
    const float* bl    = (const float*)d_in[3];
    const float* Wr    = (const float*)d_in[4];
    const float* Wlin1 = (const float*)d_in[5];
    const float* blin1 = (const float*)d_in[6];
    const float* Wlin2 = (const float*)d_in[7];
    const float* blin2 = (const float*)d_in[8];
    float* out = (float*)d_out;

    // workspace: xbuf[N*128] | agg[N*128] | ideg[N] | fhi/flo[7*16384] u16 |
    //   deg[N] | offs[N] | bcnt[NBUCK] | boffs[NBUCK+1] | gcur[NBUCK] |
    //   nbr[E] | part[E]   (~105 MB)
    float* xbuf = (float*)d_ws;
    float* agg  = xbuf + (size_t)N_NODES * HID;
    float* ideg = agg  + (size_t)N_NODES * HID;
    unsigned short* fhi = (unsigned short*)(ideg + N_NODES);
    unsigned short* flo = fhi + 7 * 16384;
    int* deg    = (int*)(flo + 7 * 16384);
    int* offs   = deg + N_NODES;
    int* bcnt   = offs + N_NODES;
    int* boffs  = bcnt + NBUCK;
    int* gcur   = boffs + NBUCK + 1;
    int* nbr    = gcur + NBUCK;
    unsigned* part = (unsigned*)(nbr + N_EDGES);

    // ---- CSR build (4-stage, write-locality-aware) + weight frag pack ----
    hipMemsetAsync(bcnt, 0, NBUCK * sizeof(int), stream);
    k_hist<<<EBLOCKS, 256, 0, stream>>>(ei + N_EDGES, bcnt, N_EDGES);
    k_bscan<<<1, 1, 0, stream>>>(bcnt, boffs, gcur);
    k_part<<<EBLOCKS, 256, 0, stream>>>(ei, gcur, part, N_EDGES);
    k_csr<<<NBUCK, 256, 0, stream>>>(part, boffs, deg, offs, ideg, nbr, N_NODES);
    k_makefrags<<<(7 * 16384 + 255) / 256, 256, 0, stream>>>(Wl, Wr, Wlin1, fhi, flo);

    // ---- layers ----
    const int mm_grid = (N_NODES + 63) / 64;       // 1563
    const int gather_grid = (N_NODES + 7) / 8;     // 12500
    for (int l = 0; l < N_GNN; ++l) {
        const float* xin = (l == 0) ? x : xbuf;
        k_gather<<<gather_grid, 256, 0, stream>>>(xin, offs, deg, ideg, nbr, agg,
                                                  N_NODES);
        k_sage_mfma<<<mm_grid, 256, 0, stream>>>(xin, agg, fhi, flo, l,
                                                 bl + (size_t)l * HID, xbuf, N_NODES);
    }
    k_final_mfma<<<mm_grid, 256, 0, stream>>>(xbuf, fhi, flo, blin1, Wlin2, blin2,
                                              out, N_NODES);
}